// Round 10
// baseline (7720.058 us; speedup 1.0000x reference)
//
#include <hip/hip_runtime.h>

#define T_STEPS 100
#define NB 256
#define CIN 700
#define CINP 704
#define HID 1024
#define NCLS 20
#define NH (NB * HID)                 // 262144
#define TNH ((long)T_STEPS * NH)      // 26,214,400

typedef __attribute__((ext_vector_type(8))) short bf16x8;
typedef __attribute__((ext_vector_type(4))) float f32x4;

__device__ inline unsigned short f2bf(float f) {
  union { float f; unsigned int u; } c; c.f = f;
  unsigned int u = c.u;
  unsigned int r = (u + 0x7FFFu + ((u >> 16) & 1u)) >> 16;
  return (unsigned short)r;
}
__device__ inline float bf2f(unsigned short h) {
  union { unsigned int u; float f; } c; c.u = ((unsigned int)h) << 16; return c.f;
}
__device__ inline f32x4 mfma16(bf16x8 a, bf16x8 b, f32x4 c) {
  return __builtin_amdgcn_mfma_f32_16x16x32_bf16(a, b, c, 0, 0, 0);
}

// ---------------------------------------------------------------------------
// Transpose + exact 3-way bf16 split: W [K][1024] fp32 -> Wh/Wm/Wl [1024][KP]
// (K-contiguous), zero-padded to KP. W == hi+mid+lo exactly (8+8+8 mantissa).
// ---------------------------------------------------------------------------
__global__ __launch_bounds__(256) void split_w(
    const float* __restrict__ W, unsigned short* __restrict__ oh,
    unsigned short* __restrict__ om, unsigned short* __restrict__ ol,
    int K, int KP) {
  __shared__ float s[32][33];
  const int k0 = blockIdx.x * 32, n0 = blockIdx.y * 32;
  const int tx = threadIdx.x & 31, ty = threadIdx.x >> 5;  // 32 x 8
#pragma unroll
  for (int i = 0; i < 4; ++i) {
    int k = k0 + ty + 8 * i;
    s[ty + 8 * i][tx] = (k < K) ? W[(long)k * HID + n0 + tx] : 0.f;
  }
  __syncthreads();
#pragma unroll
  for (int i = 0; i < 4; ++i) {
    int n = n0 + ty + 8 * i;
    float f = s[tx][ty + 8 * i];
    unsigned short h = f2bf(f);
    float r1 = f - bf2f(h);
    unsigned short m = f2bf(r1);
    float r2 = r1 - bf2f(m);
    unsigned short l = f2bf(r2);
    long o = (long)n * KP + k0 + tx;
    oh[o] = h; om[o] = m; ol[o] = l;
  }
}

// ---------------------------------------------------------------------------
// GEMM (exact-A bf16): out[MxHID] = A[Mx1024](bf16 0/1) @ (Bh+Bm+Bl)^T + bias
// B stored [1024 n][1024 k] bf16. 128x128 tile, BK=32, 4 waves each 64x64.
// ---------------------------------------------------------------------------
__global__ __launch_bounds__(256) void gemm_sw3(
    const unsigned short* __restrict__ A, const unsigned short* __restrict__ Bh,
    const unsigned short* __restrict__ Bm, const unsigned short* __restrict__ Bl,
    const float* __restrict__ bias, float* __restrict__ out, int M) {
  __shared__ unsigned short As[128][40], Bhs[128][40], Bms[128][40],
      Bls[128][40];
  const int tid = threadIdx.x;
  const int w = tid >> 6, lane = tid & 63;
  const int wm = w >> 1, wn = w & 1;
  const int l15 = lane & 15, g = lane >> 4;
  const long row0 = (long)blockIdx.x * 128;
  const int col0 = blockIdx.y * 128;
  f32x4 acc[4][4];
  const f32x4 zf = {0.f, 0.f, 0.f, 0.f};
#pragma unroll
  for (int mi = 0; mi < 4; ++mi)
#pragma unroll
    for (int ni = 0; ni < 4; ++ni) acc[mi][ni] = zf;

  for (int kt = 0; kt < HID; kt += 32) {
#pragma unroll
    for (int i = 0; i < 2; ++i) {
      int slot = tid + 256 * i;          // 0..511
      int r = slot >> 2, kk = (slot & 3) * 8;
      *(uint4*)&As[r][kk] = *(const uint4*)(A + (row0 + r) * HID + kt + kk);
      long gi = (long)(col0 + r) * HID + kt + kk;
      *(uint4*)&Bhs[r][kk] = *(const uint4*)(Bh + gi);
      *(uint4*)&Bms[r][kk] = *(const uint4*)(Bm + gi);
      *(uint4*)&Bls[r][kk] = *(const uint4*)(Bl + gi);
    }
    __syncthreads();
    bf16x8 af[4];
#pragma unroll
    for (int mi = 0; mi < 4; ++mi)
      af[mi] = *(const bf16x8*)&As[wm * 64 + mi * 16 + l15][g * 8];
#pragma unroll
    for (int ni = 0; ni < 4; ++ni) {
      int r = wn * 64 + ni * 16 + l15;
      bf16x8 bb;
      bb = *(const bf16x8*)&Bhs[r][g * 8];
#pragma unroll
      for (int mi = 0; mi < 4; ++mi) acc[mi][ni] = mfma16(af[mi], bb, acc[mi][ni]);
      bb = *(const bf16x8*)&Bms[r][g * 8];
#pragma unroll
      for (int mi = 0; mi < 4; ++mi) acc[mi][ni] = mfma16(af[mi], bb, acc[mi][ni]);
      bb = *(const bf16x8*)&Bls[r][g * 8];
#pragma unroll
      for (int mi = 0; mi < 4; ++mi) acc[mi][ni] = mfma16(af[mi], bb, acc[mi][ni]);
    }
    __syncthreads();
  }
#pragma unroll
  for (int mi = 0; mi < 4; ++mi)
#pragma unroll
    for (int ni = 0; ni < 4; ++ni) {
      int c = col0 + wn * 64 + ni * 16 + l15;
      float b = bias[c];
#pragma unroll
      for (int reg = 0; reg < 4; ++reg) {
        long r = row0 + wm * 64 + mi * 16 + g * 4 + reg;
        out[r * HID + c] = acc[mi][ni][reg] + b;
      }
    }
}

// ---------------------------------------------------------------------------
// GEMM1: xin = x @ W_in + b_in.  A = x fp32 [25600][700], split 3-way in
// staging; B = W_in 3-split [1024][704]. 6 products (>=2^-16); fp32-accum.
// Epilogue scatters r=(n*100+t) -> xin[t][n][h].
// ---------------------------------------------------------------------------
__global__ __launch_bounds__(256) void gemm_x6(
    const float* __restrict__ X, const unsigned short* __restrict__ Bh,
    const unsigned short* __restrict__ Bm, const unsigned short* __restrict__ Bl,
    const float* __restrict__ bias, float* __restrict__ out) {
  __shared__ unsigned short Ahs[128][40], Ams[128][40], Als[128][40];
  __shared__ unsigned short Bhs[128][40], Bms[128][40], Bls[128][40];
  const int tid = threadIdx.x;
  const int w = tid >> 6, lane = tid & 63;
  const int wm = w >> 1, wn = w & 1;
  const int l15 = lane & 15, g = lane >> 4;
  const long row0 = (long)blockIdx.x * 128;
  const int col0 = blockIdx.y * 128;
  f32x4 acc[4][4];
  const f32x4 zf = {0.f, 0.f, 0.f, 0.f};
#pragma unroll
  for (int mi = 0; mi < 4; ++mi)
#pragma unroll
    for (int ni = 0; ni < 4; ++ni) acc[mi][ni] = zf;

  for (int kt = 0; kt < CINP; kt += 32) {
    // A: 128 rows x 32 k fp32 -> 1024 float4 slots, 4/thread, split to 3 LDS
#pragma unroll
    for (int i = 0; i < 4; ++i) {
      int slot = tid + 256 * i;              // 0..1023
      int r = slot >> 3, kq = (slot & 7) * 4;
      float4 v = make_float4(0.f, 0.f, 0.f, 0.f);
      if (kt + kq < CIN) v = *(const float4*)(X + (row0 + r) * (long)CIN + kt + kq);
      unsigned int h0, h1, m0, m1, l0, l1;
      {
        float f0 = v.x, f1 = v.y;
        unsigned short a = f2bf(f0), b = f2bf(f1);
        float ra = f0 - bf2f(a), rb = f1 - bf2f(b);
        unsigned short c = f2bf(ra), d = f2bf(rb);
        float sa = ra - bf2f(c), sb = rb - bf2f(d);
        h0 = (unsigned int)a | ((unsigned int)b << 16);
        m0 = (unsigned int)c | ((unsigned int)d << 16);
        l0 = (unsigned int)f2bf(sa) | ((unsigned int)f2bf(sb) << 16);
      }
      {
        float f0 = v.z, f1 = v.w;
        unsigned short a = f2bf(f0), b = f2bf(f1);
        float ra = f0 - bf2f(a), rb = f1 - bf2f(b);
        unsigned short c = f2bf(ra), d = f2bf(rb);
        float sa = ra - bf2f(c), sb = rb - bf2f(d);
        h1 = (unsigned int)a | ((unsigned int)b << 16);
        m1 = (unsigned int)c | ((unsigned int)d << 16);
        l1 = (unsigned int)f2bf(sa) | ((unsigned int)f2bf(sb) << 16);
      }
      uint2 uh = {h0, h1}, um = {m0, m1}, ul = {l0, l1};
      *(uint2*)&Ahs[r][kq] = uh;
      *(uint2*)&Ams[r][kq] = um;
      *(uint2*)&Als[r][kq] = ul;
    }
    // B: 3 planes, 512 16B-slots, 2/thread
#pragma unroll
    for (int i = 0; i < 2; ++i) {
      int slot = tid + 256 * i;
      int r = slot >> 2, kk = (slot & 3) * 8;
      long gi = (long)(col0 + r) * CINP + kt + kk;
      *(uint4*)&Bhs[r][kk] = *(const uint4*)(Bh + gi);
      *(uint4*)&Bms[r][kk] = *(const uint4*)(Bm + gi);
      *(uint4*)&Bls[r][kk] = *(const uint4*)(Bl + gi);
    }
    __syncthreads();
    bf16x8 ah[4], am[4], al[4];
#pragma unroll
    for (int mi = 0; mi < 4; ++mi) {
      int r = wm * 64 + mi * 16 + l15;
      ah[mi] = *(const bf16x8*)&Ahs[r][g * 8];
      am[mi] = *(const bf16x8*)&Ams[r][g * 8];
      al[mi] = *(const bf16x8*)&Als[r][g * 8];
    }
#pragma unroll
    for (int ni = 0; ni < 4; ++ni) {
      int r = wn * 64 + ni * 16 + l15;
      bf16x8 bb;
      bb = *(const bf16x8*)&Bhs[r][g * 8];   // xh*wh + xm*wh + xl*wh
#pragma unroll
      for (int mi = 0; mi < 4; ++mi) acc[mi][ni] = mfma16(ah[mi], bb, acc[mi][ni]);
#pragma unroll
      for (int mi = 0; mi < 4; ++mi) acc[mi][ni] = mfma16(am[mi], bb, acc[mi][ni]);
#pragma unroll
      for (int mi = 0; mi < 4; ++mi) acc[mi][ni] = mfma16(al[mi], bb, acc[mi][ni]);
      bb = *(const bf16x8*)&Bms[r][g * 8];   // xh*wm + xm*wm
#pragma unroll
      for (int mi = 0; mi < 4; ++mi) acc[mi][ni] = mfma16(ah[mi], bb, acc[mi][ni]);
#pragma unroll
      for (int mi = 0; mi < 4; ++mi) acc[mi][ni] = mfma16(am[mi], bb, acc[mi][ni]);
      bb = *(const bf16x8*)&Bls[r][g * 8];   // xh*wl
#pragma unroll
      for (int mi = 0; mi < 4; ++mi) acc[mi][ni] = mfma16(ah[mi], bb, acc[mi][ni]);
    }
    __syncthreads();
  }
#pragma unroll
  for (int mi = 0; mi < 4; ++mi)
#pragma unroll
    for (int ni = 0; ni < 4; ++ni) {
      int c = col0 + wn * 64 + ni * 16 + l15;
      float b = bias[c];
#pragma unroll
      for (int reg = 0; reg < 4; ++reg) {
        long r = row0 + wm * 64 + mi * 16 + g * 4 + reg;
        int t = (int)(r % T_STEPS);
        int n = (int)(r / T_STEPS);
        out[((long)t * NB + n) * HID + c] = acc[mi][ni][reg] + b;
      }
    }
}

// ---------------------------------------------------------------------------
// Persistent recurrent scan, XCD-local: grid (32 col-tiles, 8 row-tiles).
// Dispatch id = bx + by*32 -> XCD = bx % 8: each XCD owns 4 col-tiles (128
// cols = 786 KB of weight planes, L2-resident all 100 steps) x 8 row-tiles.
// Barrier: per-WG padded flag slots; one release-store per WG, each thread
// acquire-polls one distinct slot. Bounded spin (no hang mode).
// v1 in registers; A (spikes) staged in LDS per step; accumulation order per
// output == round-4 step_mfma (ascending 32-k, hi/mid/lo) -> absmax ~0.
// ---------------------------------------------------------------------------
#define FLAG_STRIDE 16  // ints; 64 B per slot, no false sharing

__global__ __launch_bounds__(256) void scan_kernel(
    const unsigned short* __restrict__ Bh, const unsigned short* __restrict__ Bm,
    const unsigned short* __restrict__ Bl, const float* __restrict__ b_rec,
    const float* __restrict__ xin, unsigned short* __restrict__ s1,
    int* __restrict__ flags) {
  // stride 1032 shorts = 2064 B; 66048 B total -> 2 WG/CU capacity.
  __shared__ unsigned short As[32][1032];
  const int tid = threadIdx.x;
  const int w = tid >> 6, lane = tid & 63;
  const int wr = w >> 1, wc = w & 1;        // 2x2 waves
  const int l15 = lane & 15, g = lane >> 4;
  const int col0 = blockIdx.x * 32;         // x = col tile (XCD locality)
  const int row0 = blockIdx.y * 32;         // y = row tile
  const int wgid = blockIdx.x + blockIdx.y * 32;
  const int myrow16 = row0 + wr * 16;
  const int mycol = col0 + wc * 16 + l15;   // fixed column for this lane
  const float brc = b_rec[mycol];
  const unsigned short* bhp = Bh + (long)mycol * HID;
  const unsigned short* bmp = Bm + (long)mycol * HID;
  const unsigned short* blp = Bl + (long)mycol * HID;
  const int arow = wr * 16 + l15;

  f32x4 v1 = {0.f, 0.f, 0.f, 0.f};

  // ---- t = 0: inp = xin[0] + b_rec, v starts at 0 (no matmul) ----
#pragma unroll
  for (int reg = 0; reg < 4; ++reg) {
    int n = myrow16 + g * 4 + reg;
    float inp = xin[(long)n * HID + mycol] + brc;
    float h = inp * 0.5f;
    bool sp = (h >= 1.0f);
    v1[reg] = sp ? 0.0f : h;
    s1[(long)n * HID + mycol] = sp ? 0x3F80u : 0u;
  }
  // arrive(1)
  __threadfence();
  __syncthreads();
  if (tid == 0)
    __hip_atomic_store(&flags[wgid * FLAG_STRIDE], 1, __ATOMIC_RELEASE,
                       __HIP_MEMORY_SCOPE_AGENT);

  for (int t = 1; t < T_STEPS; ++t) {
    // wait: thread i polls WG i's flag (all 256 WGs covered by 256 threads)
    {
      int spins = 0;
      while (__hip_atomic_load(&flags[tid * FLAG_STRIDE], __ATOMIC_ACQUIRE,
                               __HIP_MEMORY_SCOPE_AGENT) < t &&
             spins < 200000) {
        __builtin_amdgcn_s_sleep(2);
        ++spins;
      }
      __syncthreads();
      __threadfence();
    }
    // stage A = s1[t-1] rows [row0, row0+32) : 4096 uint4, 16/thread
    const unsigned short* sp_prev = s1 + (size_t)(t - 1) * NH;
#pragma unroll
    for (int i = 0; i < 16; ++i) {
      int slot = tid + 256 * i;          // 0..4095
      int r = slot >> 7, k8 = (slot & 127) << 3;
      *(uint4*)&As[r][k8] =
          *(const uint4*)(sp_prev + (long)(row0 + r) * HID + k8);
    }
    __syncthreads();
    // prefetch xin[t] for epilogue (independent of MFMA chain)
    const float* xp = xin + (size_t)t * NH;
    float xv[4];
#pragma unroll
    for (int reg = 0; reg < 4; ++reg)
      xv[reg] = xp[(long)(myrow16 + g * 4 + reg) * HID + mycol];

    f32x4 acc = {0.f, 0.f, 0.f, 0.f};
#pragma unroll 4
    for (int kt = 0; kt < HID; kt += 32) {
      bf16x8 af = *(const bf16x8*)&As[arow][kt + g * 8];
      bf16x8 b0 = *(const bf16x8*)(bhp + kt + g * 8);
      bf16x8 b1 = *(const bf16x8*)(bmp + kt + g * 8);
      bf16x8 b2 = *(const bf16x8*)(blp + kt + g * 8);
      acc = mfma16(af, b0, acc);
      acc = mfma16(af, b1, acc);
      acc = mfma16(af, b2, acc);
    }
    // epilogue: LIF1, v1 in regs, write s1[t]
    unsigned short* so = s1 + (size_t)t * NH;
#pragma unroll
    for (int reg = 0; reg < 4; ++reg) {
      int n = myrow16 + g * 4 + reg;
      float inp = acc[reg] + brc + xv[reg];
      float h = v1[reg] + (inp - v1[reg]) * 0.5f;
      bool sp = (h >= 1.0f);
      v1[reg] = sp ? 0.0f : h;
      so[(long)n * HID + mycol] = sp ? 0x3F80u : 0u;
    }
    if (t < T_STEPS - 1) {
      __threadfence();
      __syncthreads();
      if (tid == 0)
        __hip_atomic_store(&flags[wgid * FLAG_STRIDE], t + 1, __ATOMIC_RELEASE,
                           __HIP_MEMORY_SCOPE_AGENT);
    }
  }
}

// LIF2: per-(n,h) scan over t: z -> feat spikes (bf16 0/1).
__global__ __launch_bounds__(256) void lif2_kernel(
    const float* __restrict__ z, unsigned short* __restrict__ feat) {
  long id = (long)blockIdx.x * 256 + threadIdx.x;
  float v = 0.0f;
  for (int t = 0; t < T_STEPS; ++t) {
    float x = z[(long)t * NH + id];
    float h = v + (x - v) * 0.5f;
    bool sp = (h >= 1.0f);
    v = sp ? 0.0f : h;
    feat[(long)t * NH + id] = sp ? 0x3F80u : 0u;
  }
}

// LayerNorm over last dim (1024), in place. One block (256 thr) per row.
__global__ __launch_bounds__(256) void ln_kernel(float* __restrict__ y,
                                                 const float* __restrict__ g,
                                                 const float* __restrict__ b) {
  __shared__ float red[4];
  long row = blockIdx.x;
  float* p = y + row * HID;
  int tid = threadIdx.x;
  float x[4];
#pragma unroll
  for (int i = 0; i < 4; ++i) x[i] = p[tid + 256 * i];
  float s = x[0] + x[1] + x[2] + x[3];
#pragma unroll
  for (int m = 32; m; m >>= 1) s += __shfl_xor(s, m, 64);
  if ((tid & 63) == 0) red[tid >> 6] = s;
  __syncthreads();
  float mu = (red[0] + red[1] + red[2] + red[3]) * (1.0f / HID);
  __syncthreads();
  float r0 = x[0] - mu, r1 = x[1] - mu, r2 = x[2] - mu, r3 = x[3] - mu;
  float v = r0 * r0 + r1 * r1 + r2 * r2 + r3 * r3;
#pragma unroll
  for (int m = 32; m; m >>= 1) v += __shfl_xor(v, m, 64);
  if ((tid & 63) == 0) red[tid >> 6] = v;
  __syncthreads();
  float var = (red[0] + red[1] + red[2] + red[3]) * (1.0f / HID);
  float inv = 1.0f / sqrtf(var + 1e-5f);
#pragma unroll
  for (int i = 0; i < 4; ++i) {
    int h = tid + 256 * i;
    p[h] = (x[i] - mu) * inv * g[h] + b[h];
  }
}

// Third LIF over T fused with mean over T.
__global__ __launch_bounds__(256) void lifc_kernel(
    const float* __restrict__ y, float* __restrict__ sbar) {
  long id = (long)blockIdx.x * 256 + threadIdx.x;
  float v = 0.0f, acc = 0.0f;
  for (int t = 0; t < T_STEPS; ++t) {
    float x = y[(long)t * NH + id];
    float h = v + (x - v) * 0.5f;
    if (h >= 1.0f) {
      acc += 1.0f;
      v = 0.0f;
    } else {
      v = h;
    }
  }
  sbar[id] = acc * (1.0f / T_STEPS);
}

// out[n,j] = sbar[n,:] @ W_out[:,j] + b_out[j]
__global__ __launch_bounds__(64) void out_kernel(
    const float* __restrict__ sbar, const float* __restrict__ Wout,
    const float* __restrict__ bout, float* __restrict__ out) {
  int n = blockIdx.x, j = threadIdx.x;
  if (j >= NCLS) return;
  const float* s = sbar + (long)n * HID;
  float a0 = 0.f, a1 = 0.f, a2 = 0.f, a3 = 0.f;
  for (int k = 0; k < HID; k += 4) {
    a0 += s[k + 0] * Wout[(k + 0) * NCLS + j];
    a1 += s[k + 1] * Wout[(k + 1) * NCLS + j];
    a2 += s[k + 2] * Wout[(k + 2) * NCLS + j];
    a3 += s[k + 3] * Wout[(k + 3) * NCLS + j];
  }
  out[n * NCLS + j] = ((a0 + a1) + (a2 + a3)) + bout[j];
}

// ---------------------------------------------------------------------------
extern "C" void kernel_launch(void* const* d_in, const int* in_sizes, int n_in,
                              void* d_out, int out_size, void* d_ws,
                              size_t ws_size, hipStream_t stream) {
  const float* x = (const float*)d_in[0];
  const float* W_in = (const float*)d_in[1];
  const float* b_in = (const float*)d_in[2];
  const float* W_rec = (const float*)d_in[3];
  const float* b_rec = (const float*)d_in[4];
  const float* W2 = (const float*)d_in[5];
  const float* b2 = (const float*)d_in[6];
  const float* W3 = (const float*)d_in[7];
  const float* b3 = (const float*)d_in[8];
  const float* ln_g = (const float*)d_in[9];
  const float* ln_b = (const float*)d_in[10];
  const float* W_out = (const float*)d_in[11];
  const float* b_out = (const float*)d_in[12];
  float* out = (float*)d_out;
  (void)in_sizes; (void)n_in; (void)out_size; (void)ws_size;

  // Workspace (~183 MB; rounds 4/7 passed with this footprint):
  //   xin buffer [TNH f32] holds: xin -> (after scan) z -> (after lif2) y
  //   s1  buffer [TNH u16] holds: s1 spikes -> (after z-GEMM) feat spikes
  char* ws = (char*)d_ws;
  size_t off = 0;
  auto carve = [&](size_t bytes) -> void* {
    void* p = (void*)(ws + off);
    off += (bytes + 255) & ~(size_t)255;
    return p;
  };
  unsigned short* wih = (unsigned short*)carve((size_t)HID * CINP * 2);
  unsigned short* wim = (unsigned short*)carve((size_t)HID * CINP * 2);
  unsigned short* wil = (unsigned short*)carve((size_t)HID * CINP * 2);
  unsigned short* wrh = (unsigned short*)carve((size_t)HID * HID * 2);
  unsigned short* wrm = (unsigned short*)carve((size_t)HID * HID * 2);
  unsigned short* wrl = (unsigned short*)carve((size_t)HID * HID * 2);
  unsigned short* w2h = (unsigned short*)carve((size_t)HID * HID * 2);
  unsigned short* w2m = (unsigned short*)carve((size_t)HID * HID * 2);
  unsigned short* w2l = (unsigned short*)carve((size_t)HID * HID * 2);
  unsigned short* w3h = (unsigned short*)carve((size_t)HID * HID * 2);
  unsigned short* w3m = (unsigned short*)carve((size_t)HID * HID * 2);
  unsigned short* w3l = (unsigned short*)carve((size_t)HID * HID * 2);
  float* xin = (float*)carve((size_t)TNH * 4);                   // xin / z / y
  unsigned short* s1 = (unsigned short*)carve((size_t)TNH * 2);  // s1 / feat
  float* sbar = (float*)carve((size_t)NH * 4);
  int* flags = (int*)carve(256 * FLAG_STRIDE * 4);               // 16 KB

  // weight splits (transpose to [N][K], exact hi/mid/lo)
  split_w<<<dim3(CINP / 32, HID / 32), 256, 0, stream>>>(W_in, wih, wim, wil, CIN, CINP);
  split_w<<<dim3(HID / 32, HID / 32), 256, 0, stream>>>(W_rec, wrh, wrm, wrl, HID, HID);
  split_w<<<dim3(HID / 32, HID / 32), 256, 0, stream>>>(W2, w2h, w2m, w2l, HID, HID);
  split_w<<<dim3(HID / 32, HID / 32), 256, 0, stream>>>(W3, w3h, w3m, w3l, HID, HID);

  // xin[t][n][h] = x @ W_in + b_in  (6-product exact-split MFMA)
  gemm_x6<<<dim3(25600 / 128, HID / 128), 256, 0, stream>>>(x, wih, wim, wil, b_in, xin);

  // persistent recurrent scan (t = 0..99) in ONE launch, XCD-local cols
  hipMemsetAsync(flags, 0, 256 * FLAG_STRIDE * 4, stream);
  scan_kernel<<<dim3(32, 8), 256, 0, stream>>>(wrh, wrm, wrl, b_rec, xin, s1, flags);

  // z = s1_all @ W2 + b2 (parallel over t) -> overwrite xin (dead after scan)
  gemm_sw3<<<dim3(25600 / 128, HID / 128), 256, 0, stream>>>(s1, w2h, w2m, w2l, b2, xin, 25600);
  // LIF2 scan: z (in xin) -> feat spikes, overwriting s1 (dead after z-GEMM)
  lif2_kernel<<<dim3(NH / 256), 256, 0, stream>>>(xin, s1);

  // y = feat @ W3 + b3 -> back into xin (z dead after lif2), then LN
  gemm_sw3<<<dim3(25600 / 128, HID / 128), 256, 0, stream>>>(s1, w3h, w3m, w3l, b3, xin, 25600);
  ln_kernel<<<dim3(25600), 256, 0, stream>>>(xin, ln_g, ln_b);
  lifc_kernel<<<dim3(NH / 256), 256, 0, stream>>>(xin, sbar);
  out_kernel<<<dim3(NB), 64, 0, stream>>>(sbar, W_out, b_out, out);
}

// Round 11
// 2348.198 us; speedup vs baseline: 3.2877x; 3.2877x over previous
//
#include <hip/hip_runtime.h>

#define T_STEPS 100
#define NB 256
#define CIN 700
#define CINP 704
#define HID 1024
#define NCLS 20
#define NH (NB * HID)                 // 262144
#define TNH ((long)T_STEPS * NH)      // 26,214,400

typedef __attribute__((ext_vector_type(8))) short bf16x8;
typedef __attribute__((ext_vector_type(4))) float f32x4;

__device__ inline unsigned short f2bf(float f) {
  union { float f; unsigned int u; } c; c.f = f;
  unsigned int u = c.u;
  unsigned int r = (u + 0x7FFFu + ((u >> 16) & 1u)) >> 16;
  return (unsigned short)r;
}
__device__ inline float bf2f(unsigned short h) {
  union { unsigned int u; float f; } c; c.u = ((unsigned int)h) << 16; return c.f;
}
__device__ inline f32x4 mfma16(bf16x8 a, bf16x8 b, f32x4 c) {
  return __builtin_amdgcn_mfma_f32_16x16x32_bf16(a, b, c, 0, 0, 0);
}

// ---------------------------------------------------------------------------
// Transpose + exact 3-way bf16 split: W [K][1024] fp32 -> Wh/Wm/Wl [1024][KP]
// (K-contiguous), zero-padded to KP. W == hi+mid+lo exactly (8+8+8 mantissa).
// ---------------------------------------------------------------------------
__global__ __launch_bounds__(256) void split_w(
    const float* __restrict__ W, unsigned short* __restrict__ oh,
    unsigned short* __restrict__ om, unsigned short* __restrict__ ol,
    int K, int KP) {
  __shared__ float s[32][33];
  const int k0 = blockIdx.x * 32, n0 = blockIdx.y * 32;
  const int tx = threadIdx.x & 31, ty = threadIdx.x >> 5;  // 32 x 8
#pragma unroll
  for (int i = 0; i < 4; ++i) {
    int k = k0 + ty + 8 * i;
    s[ty + 8 * i][tx] = (k < K) ? W[(long)k * HID + n0 + tx] : 0.f;
  }
  __syncthreads();
#pragma unroll
  for (int i = 0; i < 4; ++i) {
    int n = n0 + ty + 8 * i;
    float f = s[tx][ty + 8 * i];
    unsigned short h = f2bf(f);
    float r1 = f - bf2f(h);
    unsigned short m = f2bf(r1);
    float r2 = r1 - bf2f(m);
    unsigned short l = f2bf(r2);
    long o = (long)n * KP + k0 + tx;
    oh[o] = h; om[o] = m; ol[o] = l;
  }
}

// ---------------------------------------------------------------------------
// GEMM (exact-A bf16): out[MxHID] = A[Mx1024](bf16 0/1) @ (Bh+Bm+Bl)^T + bias
// B stored [1024 n][1024 k] bf16. 128x128 tile, BK=32, 4 waves each 64x64.
// ---------------------------------------------------------------------------
__global__ __launch_bounds__(256) void gemm_sw3(
    const unsigned short* __restrict__ A, const unsigned short* __restrict__ Bh,
    const unsigned short* __restrict__ Bm, const unsigned short* __restrict__ Bl,
    const float* __restrict__ bias, float* __restrict__ out, int M) {
  __shared__ unsigned short As[128][40], Bhs[128][40], Bms[128][40],
      Bls[128][40];
  const int tid = threadIdx.x;
  const int w = tid >> 6, lane = tid & 63;
  const int wm = w >> 1, wn = w & 1;
  const int l15 = lane & 15, g = lane >> 4;
  const long row0 = (long)blockIdx.x * 128;
  const int col0 = blockIdx.y * 128;
  f32x4 acc[4][4];
  const f32x4 zf = {0.f, 0.f, 0.f, 0.f};
#pragma unroll
  for (int mi = 0; mi < 4; ++mi)
#pragma unroll
    for (int ni = 0; ni < 4; ++ni) acc[mi][ni] = zf;

  for (int kt = 0; kt < HID; kt += 32) {
#pragma unroll
    for (int i = 0; i < 2; ++i) {
      int slot = tid + 256 * i;          // 0..511
      int r = slot >> 2, kk = (slot & 3) * 8;
      *(uint4*)&As[r][kk] = *(const uint4*)(A + (row0 + r) * HID + kt + kk);
      long gi = (long)(col0 + r) * HID + kt + kk;
      *(uint4*)&Bhs[r][kk] = *(const uint4*)(Bh + gi);
      *(uint4*)&Bms[r][kk] = *(const uint4*)(Bm + gi);
      *(uint4*)&Bls[r][kk] = *(const uint4*)(Bl + gi);
    }
    __syncthreads();
    bf16x8 af[4];
#pragma unroll
    for (int mi = 0; mi < 4; ++mi)
      af[mi] = *(const bf16x8*)&As[wm * 64 + mi * 16 + l15][g * 8];
#pragma unroll
    for (int ni = 0; ni < 4; ++ni) {
      int r = wn * 64 + ni * 16 + l15;
      bf16x8 bb;
      bb = *(const bf16x8*)&Bhs[r][g * 8];
#pragma unroll
      for (int mi = 0; mi < 4; ++mi) acc[mi][ni] = mfma16(af[mi], bb, acc[mi][ni]);
      bb = *(const bf16x8*)&Bms[r][g * 8];
#pragma unroll
      for (int mi = 0; mi < 4; ++mi) acc[mi][ni] = mfma16(af[mi], bb, acc[mi][ni]);
      bb = *(const bf16x8*)&Bls[r][g * 8];
#pragma unroll
      for (int mi = 0; mi < 4; ++mi) acc[mi][ni] = mfma16(af[mi], bb, acc[mi][ni]);
    }
    __syncthreads();
  }
#pragma unroll
  for (int mi = 0; mi < 4; ++mi)
#pragma unroll
    for (int ni = 0; ni < 4; ++ni) {
      int c = col0 + wn * 64 + ni * 16 + l15;
      float b = bias[c];
#pragma unroll
      for (int reg = 0; reg < 4; ++reg) {
        long r = row0 + wm * 64 + mi * 16 + g * 4 + reg;
        out[r * HID + c] = acc[mi][ni][reg] + b;
      }
    }
}

// ---------------------------------------------------------------------------
// GEMM1: xin = x @ W_in + b_in.  A = x fp32 [25600][700], split 3-way in
// staging; B = W_in 3-split [1024][704]. 6 products (>=2^-16); fp32-accum.
// Epilogue scatters r=(n*100+t) -> xin[t][n][h].
// ---------------------------------------------------------------------------
__global__ __launch_bounds__(256) void gemm_x6(
    const float* __restrict__ X, const unsigned short* __restrict__ Bh,
    const unsigned short* __restrict__ Bm, const unsigned short* __restrict__ Bl,
    const float* __restrict__ bias, float* __restrict__ out) {
  __shared__ unsigned short Ahs[128][40], Ams[128][40], Als[128][40];
  __shared__ unsigned short Bhs[128][40], Bms[128][40], Bls[128][40];
  const int tid = threadIdx.x;
  const int w = tid >> 6, lane = tid & 63;
  const int wm = w >> 1, wn = w & 1;
  const int l15 = lane & 15, g = lane >> 4;
  const long row0 = (long)blockIdx.x * 128;
  const int col0 = blockIdx.y * 128;
  f32x4 acc[4][4];
  const f32x4 zf = {0.f, 0.f, 0.f, 0.f};
#pragma unroll
  for (int mi = 0; mi < 4; ++mi)
#pragma unroll
    for (int ni = 0; ni < 4; ++ni) acc[mi][ni] = zf;

  for (int kt = 0; kt < CINP; kt += 32) {
    // A: 128 rows x 32 k fp32 -> 1024 float4 slots, 4/thread, split to 3 LDS
#pragma unroll
    for (int i = 0; i < 4; ++i) {
      int slot = tid + 256 * i;              // 0..1023
      int r = slot >> 3, kq = (slot & 7) * 4;
      float4 v = make_float4(0.f, 0.f, 0.f, 0.f);
      if (kt + kq < CIN) v = *(const float4*)(X + (row0 + r) * (long)CIN + kt + kq);
      unsigned int h0, h1, m0, m1, l0, l1;
      {
        float f0 = v.x, f1 = v.y;
        unsigned short a = f2bf(f0), b = f2bf(f1);
        float ra = f0 - bf2f(a), rb = f1 - bf2f(b);
        unsigned short c = f2bf(ra), d = f2bf(rb);
        float sa = ra - bf2f(c), sb = rb - bf2f(d);
        h0 = (unsigned int)a | ((unsigned int)b << 16);
        m0 = (unsigned int)c | ((unsigned int)d << 16);
        l0 = (unsigned int)f2bf(sa) | ((unsigned int)f2bf(sb) << 16);
      }
      {
        float f0 = v.z, f1 = v.w;
        unsigned short a = f2bf(f0), b = f2bf(f1);
        float ra = f0 - bf2f(a), rb = f1 - bf2f(b);
        unsigned short c = f2bf(ra), d = f2bf(rb);
        float sa = ra - bf2f(c), sb = rb - bf2f(d);
        h1 = (unsigned int)a | ((unsigned int)b << 16);
        m1 = (unsigned int)c | ((unsigned int)d << 16);
        l1 = (unsigned int)f2bf(sa) | ((unsigned int)f2bf(sb) << 16);
      }
      uint2 uh = {h0, h1}, um = {m0, m1}, ul = {l0, l1};
      *(uint2*)&Ahs[r][kq] = uh;
      *(uint2*)&Ams[r][kq] = um;
      *(uint2*)&Als[r][kq] = ul;
    }
    // B: 3 planes, 512 16B-slots, 2/thread
#pragma unroll
    for (int i = 0; i < 2; ++i) {
      int slot = tid + 256 * i;
      int r = slot >> 2, kk = (slot & 3) * 8;
      long gi = (long)(col0 + r) * CINP + kt + kk;
      *(uint4*)&Bhs[r][kk] = *(const uint4*)(Bh + gi);
      *(uint4*)&Bms[r][kk] = *(const uint4*)(Bm + gi);
      *(uint4*)&Bls[r][kk] = *(const uint4*)(Bl + gi);
    }
    __syncthreads();
    bf16x8 ah[4], am[4], al[4];
#pragma unroll
    for (int mi = 0; mi < 4; ++mi) {
      int r = wm * 64 + mi * 16 + l15;
      ah[mi] = *(const bf16x8*)&Ahs[r][g * 8];
      am[mi] = *(const bf16x8*)&Ams[r][g * 8];
      al[mi] = *(const bf16x8*)&Als[r][g * 8];
    }
#pragma unroll
    for (int ni = 0; ni < 4; ++ni) {
      int r = wn * 64 + ni * 16 + l15;
      bf16x8 bb;
      bb = *(const bf16x8*)&Bhs[r][g * 8];   // xh*wh + xm*wh + xl*wh
#pragma unroll
      for (int mi = 0; mi < 4; ++mi) acc[mi][ni] = mfma16(ah[mi], bb, acc[mi][ni]);
#pragma unroll
      for (int mi = 0; mi < 4; ++mi) acc[mi][ni] = mfma16(am[mi], bb, acc[mi][ni]);
#pragma unroll
      for (int mi = 0; mi < 4; ++mi) acc[mi][ni] = mfma16(al[mi], bb, acc[mi][ni]);
      bb = *(const bf16x8*)&Bms[r][g * 8];   // xh*wm + xm*wm
#pragma unroll
      for (int mi = 0; mi < 4; ++mi) acc[mi][ni] = mfma16(ah[mi], bb, acc[mi][ni]);
#pragma unroll
      for (int mi = 0; mi < 4; ++mi) acc[mi][ni] = mfma16(am[mi], bb, acc[mi][ni]);
      bb = *(const bf16x8*)&Bls[r][g * 8];   // xh*wl
#pragma unroll
      for (int mi = 0; mi < 4; ++mi) acc[mi][ni] = mfma16(ah[mi], bb, acc[mi][ni]);
    }
    __syncthreads();
  }
#pragma unroll
  for (int mi = 0; mi < 4; ++mi)
#pragma unroll
    for (int ni = 0; ni < 4; ++ni) {
      int c = col0 + wn * 64 + ni * 16 + l15;
      float b = bias[c];
#pragma unroll
      for (int reg = 0; reg < 4; ++reg) {
        long r = row0 + wm * 64 + mi * 16 + g * 4 + reg;
        int t = (int)(r % T_STEPS);
        int n = (int)(r / T_STEPS);
        out[((long)t * NB + n) * HID + c] = acc[mi][ni][reg] + b;
      }
    }
}

// ---------------------------------------------------------------------------
// Recurrent step v2: one launch per step (launch boundary = HW device barrier,
// ~10x cheaper than in-kernel device-scope fences — r10 measured 65 us/step
// of pure sync overhead in the persistent variant).
// Grid (32 col-tiles, 8 row-tiles) = 256 WGs -> full CU coverage; col-tile is
// the fast axis so XCD = id%8 = col-tile%8 -> each XCD re-reads the SAME
// 786 KB weight slice every launch (L2 stays hot across launches, r10
// verified FETCH drop). A (spikes) staged once in LDS (single barrier);
// B planes read direct from L2 as fragments; v1 round-trips global (2MB).
// Accumulation order per output: ascending 32-k blocks, hi/mid/lo chained
// -> bit-identical spikes to rounds 4/7/10 (all absmax 0.0).
// ---------------------------------------------------------------------------
__global__ __launch_bounds__(256) void step2(
    const unsigned short* __restrict__ Sprev,
    const unsigned short* __restrict__ Bh, const unsigned short* __restrict__ Bm,
    const unsigned short* __restrict__ Bl, const float* __restrict__ b_rec,
    const float* __restrict__ xin_t, float* __restrict__ v1,
    unsigned short* __restrict__ Sout) {
  // stride 1032 shorts = 2064 B; 66048 B total (2 WG/CU capacity; grid=1/CU).
  __shared__ unsigned short As[32][1032];
  const int tid = threadIdx.x;
  const int w = tid >> 6, lane = tid & 63;
  const int wr = w >> 1, wc = w & 1;        // 2x2 waves of 16x16
  const int l15 = lane & 15, g = lane >> 4;
  const int col0 = blockIdx.x * 32;         // fast axis = col (XCD locality)
  const int row0 = blockIdx.y * 32;
  const int myrow16 = row0 + wr * 16;
  const int mycol = col0 + wc * 16 + l15;   // fixed column for this lane
  const float brc = b_rec[mycol];
  const unsigned short* bhp = Bh + (long)mycol * HID;
  const unsigned short* bmp = Bm + (long)mycol * HID;
  const unsigned short* blp = Bl + (long)mycol * HID;
  const int arow = wr * 16 + l15;

  // stage A = Sprev rows [row0, row0+32) x 1024 k : 4096 uint4, 16/thread
#pragma unroll
  for (int i = 0; i < 16; ++i) {
    int slot = tid + 256 * i;            // 0..4095
    int r = slot >> 7, k8 = (slot & 127) << 3;
    *(uint4*)&As[r][k8] = *(const uint4*)(Sprev + (long)(row0 + r) * HID + k8);
  }
  __syncthreads();

  // xin[t] prefetch (independent of MFMA chain)
  float xv[4];
#pragma unroll
  for (int reg = 0; reg < 4; ++reg)
    xv[reg] = xin_t[(long)(myrow16 + g * 4 + reg) * HID + mycol];

  f32x4 acc = {0.f, 0.f, 0.f, 0.f};
#pragma unroll 4
  for (int kt = 0; kt < HID; kt += 32) {
    bf16x8 af = *(const bf16x8*)&As[arow][kt + g * 8];
    bf16x8 b0 = *(const bf16x8*)(bhp + kt + g * 8);
    bf16x8 b1 = *(const bf16x8*)(bmp + kt + g * 8);
    bf16x8 b2 = *(const bf16x8*)(blp + kt + g * 8);
    acc = mfma16(af, b0, acc);
    acc = mfma16(af, b1, acc);
    acc = mfma16(af, b2, acc);
  }

  // epilogue: LIF1 (v1 global round-trip), write spikes
#pragma unroll
  for (int reg = 0; reg < 4; ++reg) {
    int n = myrow16 + g * 4 + reg;
    long idx = (long)n * HID + mycol;
    float inp = acc[reg] + brc + xv[reg];
    float v = v1[idx];
    float h = v + (inp - v) * 0.5f;
    bool sp = (h >= 1.0f);
    v1[idx] = sp ? 0.0f : h;
    Sout[idx] = sp ? 0x3F80u : 0u;
  }
}

// LIF1 at t=0: inp = xin[0] + b_rec, v1 starts at 0.
__global__ __launch_bounds__(256) void lif_prologue(
    const float* __restrict__ xin0, const float* __restrict__ b_rec,
    float* __restrict__ v1, unsigned short* __restrict__ s0) {
  long id = (long)blockIdx.x * 256 + threadIdx.x;
  float inp = xin0[id] + b_rec[id & (HID - 1)];
  float h = inp * 0.5f;
  bool sp = (h >= 1.0f);
  v1[id] = sp ? 0.0f : h;
  s0[id] = sp ? 0x3F80u : 0u;
}

// LIF2: per-(n,h) scan over t: z -> feat spikes (bf16 0/1).
__global__ __launch_bounds__(256) void lif2_kernel(
    const float* __restrict__ z, unsigned short* __restrict__ feat) {
  long id = (long)blockIdx.x * 256 + threadIdx.x;
  float v = 0.0f;
  for (int t = 0; t < T_STEPS; ++t) {
    float x = z[(long)t * NH + id];
    float h = v + (x - v) * 0.5f;
    bool sp = (h >= 1.0f);
    v = sp ? 0.0f : h;
    feat[(long)t * NH + id] = sp ? 0x3F80u : 0u;
  }
}

// LayerNorm over last dim (1024), in place. One block (256 thr) per row.
__global__ __launch_bounds__(256) void ln_kernel(float* __restrict__ y,
                                                 const float* __restrict__ g,
                                                 const float* __restrict__ b) {
  __shared__ float red[4];
  long row = blockIdx.x;
  float* p = y + row * HID;
  int tid = threadIdx.x;
  float x[4];
#pragma unroll
  for (int i = 0; i < 4; ++i) x[i] = p[tid + 256 * i];
  float s = x[0] + x[1] + x[2] + x[3];
#pragma unroll
  for (int m = 32; m; m >>= 1) s += __shfl_xor(s, m, 64);
  if ((tid & 63) == 0) red[tid >> 6] = s;
  __syncthreads();
  float mu = (red[0] + red[1] + red[2] + red[3]) * (1.0f / HID);
  __syncthreads();
  float r0 = x[0] - mu, r1 = x[1] - mu, r2 = x[2] - mu, r3 = x[3] - mu;
  float v = r0 * r0 + r1 * r1 + r2 * r2 + r3 * r3;
#pragma unroll
  for (int m = 32; m; m >>= 1) v += __shfl_xor(v, m, 64);
  if ((tid & 63) == 0) red[tid >> 6] = v;
  __syncthreads();
  float var = (red[0] + red[1] + red[2] + red[3]) * (1.0f / HID);
  float inv = 1.0f / sqrtf(var + 1e-5f);
#pragma unroll
  for (int i = 0; i < 4; ++i) {
    int h = tid + 256 * i;
    p[h] = (x[i] - mu) * inv * g[h] + b[h];
  }
}

// Third LIF over T fused with mean over T.
__global__ __launch_bounds__(256) void lifc_kernel(
    const float* __restrict__ y, float* __restrict__ sbar) {
  long id = (long)blockIdx.x * 256 + threadIdx.x;
  float v = 0.0f, acc = 0.0f;
  for (int t = 0; t < T_STEPS; ++t) {
    float x = y[(long)t * NH + id];
    float h = v + (x - v) * 0.5f;
    if (h >= 1.0f) {
      acc += 1.0f;
      v = 0.0f;
    } else {
      v = h;
    }
  }
  sbar[id] = acc * (1.0f / T_STEPS);
}

// out[n,j] = sbar[n,:] @ W_out[:,j] + b_out[j]
__global__ __launch_bounds__(64) void out_kernel(
    const float* __restrict__ sbar, const float* __restrict__ Wout,
    const float* __restrict__ bout, float* __restrict__ out) {
  int n = blockIdx.x, j = threadIdx.x;
  if (j >= NCLS) return;
  const float* s = sbar + (long)n * HID;
  float a0 = 0.f, a1 = 0.f, a2 = 0.f, a3 = 0.f;
  for (int k = 0; k < HID; k += 4) {
    a0 += s[k + 0] * Wout[(k + 0) * NCLS + j];
    a1 += s[k + 1] * Wout[(k + 1) * NCLS + j];
    a2 += s[k + 2] * Wout[(k + 2) * NCLS + j];
    a3 += s[k + 3] * Wout[(k + 3) * NCLS + j];
  }
  out[n * NCLS + j] = ((a0 + a1) + (a2 + a3)) + bout[j];
}

// ---------------------------------------------------------------------------
extern "C" void kernel_launch(void* const* d_in, const int* in_sizes, int n_in,
                              void* d_out, int out_size, void* d_ws,
                              size_t ws_size, hipStream_t stream) {
  const float* x = (const float*)d_in[0];
  const float* W_in = (const float*)d_in[1];
  const float* b_in = (const float*)d_in[2];
  const float* W_rec = (const float*)d_in[3];
  const float* b_rec = (const float*)d_in[4];
  const float* W2 = (const float*)d_in[5];
  const float* b2 = (const float*)d_in[6];
  const float* W3 = (const float*)d_in[7];
  const float* b3 = (const float*)d_in[8];
  const float* ln_g = (const float*)d_in[9];
  const float* ln_b = (const float*)d_in[10];
  const float* W_out = (const float*)d_in[11];
  const float* b_out = (const float*)d_in[12];
  float* out = (float*)d_out;
  (void)in_sizes; (void)n_in; (void)out_size; (void)ws_size;

  // Workspace (~184 MB; rounds 4/7/10 passed with this footprint):
  //   xin buffer [TNH f32] holds: xin -> (after scan) z -> (after lif2) y
  //   s1  buffer [TNH u16] holds: s1 spikes -> (after z-GEMM) feat spikes
  char* ws = (char*)d_ws;
  size_t off = 0;
  auto carve = [&](size_t bytes) -> void* {
    void* p = (void*)(ws + off);
    off += (bytes + 255) & ~(size_t)255;
    return p;
  };
  unsigned short* wih = (unsigned short*)carve((size_t)HID * CINP * 2);
  unsigned short* wim = (unsigned short*)carve((size_t)HID * CINP * 2);
  unsigned short* wil = (unsigned short*)carve((size_t)HID * CINP * 2);
  unsigned short* wrh = (unsigned short*)carve((size_t)HID * HID * 2);
  unsigned short* wrm = (unsigned short*)carve((size_t)HID * HID * 2);
  unsigned short* wrl = (unsigned short*)carve((size_t)HID * HID * 2);
  unsigned short* w2h = (unsigned short*)carve((size_t)HID * HID * 2);
  unsigned short* w2m = (unsigned short*)carve((size_t)HID * HID * 2);
  unsigned short* w2l = (unsigned short*)carve((size_t)HID * HID * 2);
  unsigned short* w3h = (unsigned short*)carve((size_t)HID * HID * 2);
  unsigned short* w3m = (unsigned short*)carve((size_t)HID * HID * 2);
  unsigned short* w3l = (unsigned short*)carve((size_t)HID * HID * 2);
  float* xin = (float*)carve((size_t)TNH * 4);                   // xin / z / y
  unsigned short* s1 = (unsigned short*)carve((size_t)TNH * 2);  // s1 / feat
  float* v1 = (float*)carve((size_t)NH * 4);
  float* sbar = (float*)carve((size_t)NH * 4);

  // weight splits (transpose to [N][K], exact hi/mid/lo)
  split_w<<<dim3(CINP / 32, HID / 32), 256, 0, stream>>>(W_in, wih, wim, wil, CIN, CINP);
  split_w<<<dim3(HID / 32, HID / 32), 256, 0, stream>>>(W_rec, wrh, wrm, wrl, HID, HID);
  split_w<<<dim3(HID / 32, HID / 32), 256, 0, stream>>>(W2, w2h, w2m, w2l, HID, HID);
  split_w<<<dim3(HID / 32, HID / 32), 256, 0, stream>>>(W3, w3h, w3m, w3l, HID, HID);

  // xin[t][n][h] = x @ W_in + b_in  (6-product exact-split MFMA)
  gemm_x6<<<dim3(25600 / 128, HID / 128), 256, 0, stream>>>(x, wih, wim, wil, b_in, xin);

  // t=0 prologue, then 99 one-launch-per-step MFMA steps
  lif_prologue<<<dim3(NH / 256), 256, 0, stream>>>(xin, b_rec, v1, s1);
  for (int t = 1; t < T_STEPS; ++t) {
    step2<<<dim3(32, 8), 256, 0, stream>>>(
        s1 + (size_t)(t - 1) * NH, wrh, wrm, wrl, b_rec,
        xin + (size_t)t * NH, v1, s1 + (size_t)t * NH);
  }

  // z = s1_all @ W2 + b2 (parallel over t) -> overwrite xin (dead after scan)
  gemm_sw3<<<dim3(25600 / 128, HID / 128), 256, 0, stream>>>(s1, w2h, w2m, w2l, b2, xin, 25600);
  // LIF2 scan: z (in xin) -> feat spikes, overwriting s1 (dead after z-GEMM)
  lif2_kernel<<<dim3(NH / 256), 256, 0, stream>>>(xin, s1);

  // y = feat @ W3 + b3 -> back into xin (z dead after lif2), then LN
  gemm_sw3<<<dim3(25600 / 128, HID / 128), 256, 0, stream>>>(s1, w3h, w3m, w3l, b3, xin, 25600);
  ln_kernel<<<dim3(25600), 256, 0, stream>>>(xin, ln_g, ln_b);
  lifc_kernel<<<dim3(NH / 256), 256, 0, stream>>>(xin, sbar);
  out_kernel<<<dim3(NB), 64, 0, stream>>>(sbar, W_out, b_out, out);
}